// Round 9
// baseline (252.822 us; speedup 1.0000x reference)
//
#include <hip/hip_runtime.h>
#include <hip/hip_fp16.h>

// GCN: N=50000 nodes, E=800000 edges, 64 -> 96 -> 96 -> 32, fp32.
// R8: gather rework. (a) degree-sorted processing order: pass2 sorts each
// 98-node bucket by degree (LDS) -> perm[]; waves get equal-cnt nodes
// (was ~1.3-1.6x divergence inflation). (b) XCD channel slicing: slice=bid&7
// owns 1/8 of every row's channels -> per-XCD random working set 3.2MB fits
// 4MB L2 (was 6.4/9.6MB -> all LLC misses, FETCH 44/66MB). fp16 rows padded
// 96->128 halves so slices divide evenly; 2 lanes/node (srcs broadcast).
// Pipeline:
//   pass1: bucket edges by dst/98; pass2: CSR + dinv + perm + u_h=fp16(di*x)
//   B1 = gather<64>(u_h);  g1_h = fp16pad128(di*relu(di*(B1@W1)+b1))
//   B2 = gather<128>(g1_h); h2 = relu(di*(B2@W2)+b2); out = h2@Wfc+bfc

constexpr int NN = 50000;
constexpr int NE = 800000;
constexpr int NB = 512;     // buckets
constexpr int NPB = 98;     // nodes per bucket (512*98 = 50176 >= NN)
constexpr int BCAP = 2048;  // max edges per bucket (mean 1563; verified fit)
constexpr int EPB = 8192;   // edges per pass1 block
constexpr int P1B = 1024;   // pass1 block size
constexpr int NP1 = (NE + EPB - 1) / EPB;  // 98 blocks

__global__ void zero_bcnt(int* bcnt) {
  int i = threadIdx.x;
  if (i < NB) bcnt[i] = 0;
}

// ---------------- CSR pass 1: block-local sort + bulk reservation ----------
__global__ __launch_bounds__(P1B) void csr_pass1(const int* __restrict__ ei,
                                                 int* __restrict__ bcnt,
                                                 unsigned* __restrict__ bbuf) {
  __shared__ unsigned sorted[EPB];  // 32KB
  __shared__ int hist[NB];
  __shared__ int lofs[NB];
  __shared__ int cursor[NB];
  __shared__ int gbase[NB];
  const int t = threadIdx.x;
  const int e0 = blockIdx.x * EPB;
  const int ecnt = min(EPB, NE - e0);

  for (int i = t; i < NB; i += P1B) hist[i] = 0;
  __syncthreads();

  for (int i = t; i < ecnt; i += P1B) {
    unsigned dst = (unsigned)ei[NE + e0 + i];
    atomicAdd(&hist[dst / NPB], 1);
  }
  __syncthreads();

  if (t < NB) lofs[t] = hist[t];
  __syncthreads();
  for (int off = 1; off < NB; off <<= 1) {
    int v = 0;
    if (t < NB && t >= off) v = lofs[t - off];
    __syncthreads();
    if (t < NB) lofs[t] += v;
    __syncthreads();
  }
  if (t < NB) {
    int ex = lofs[t] - hist[t];  // exclusive
    lofs[t] = ex;
    cursor[t] = ex;
    gbase[t] = atomicAdd(&bcnt[t], hist[t]);
  }
  __syncthreads();

  for (int i = t; i < ecnt; i += P1B) {
    unsigned src = (unsigned)ei[e0 + i];
    unsigned dst = (unsigned)ei[NE + e0 + i];
    unsigned b = dst / NPB;
    unsigned dl = dst - b * NPB;
    int pos = atomicAdd(&cursor[b], 1);
    sorted[pos] = (b << 23) | (dl << 16) | src;
  }
  __syncthreads();

  for (int i = t; i < ecnt; i += P1B) {
    unsigned pw = sorted[i];
    unsigned b = pw >> 23;
    int off_in_b = gbase[b] + (i - lofs[b]);
    if (off_in_b < BCAP)
      bbuf[b * BCAP + off_in_b] = pw & 0x007FFFFFu;  // (dl<<16)|src
  }
}

// ------- CSR pass 2: per-bucket LDS sort + CSR + degree-sorted perm -------
__global__ __launch_bounds__(256) void csr_pass2(
    const int* __restrict__ bcnt, const unsigned* __restrict__ bbuf,
    const float* __restrict__ x, int* __restrict__ row_start,
    int* __restrict__ counts, float* __restrict__ dinv,
    __half* __restrict__ u, unsigned short* __restrict__ srcs,
    unsigned* __restrict__ perm) {
  __shared__ int s_red[256];
  __shared__ int s_cnt[128];
  __shared__ int s_scan[128];
  __shared__ int s_cur[128];
  __shared__ float s_dinv[128];
  __shared__ unsigned short s_sorted[BCAP];
  __shared__ int d_hist[64];
  __shared__ int d_cur[64];
  __shared__ int s_permL[NPB];
  const int b = blockIdx.x, t = threadIdx.x;
  const int cnt_b = min(bcnt[b], BCAP);

  int acc = 0;
  for (int j = t; j < b; j += 256) acc += min(bcnt[j], BCAP);
  s_red[t] = acc;
  __syncthreads();
  for (int off = 128; off > 0; off >>= 1) {
    if (t < off) s_red[t] += s_red[t + off];
    __syncthreads();
  }
  const int base = s_red[0];

  if (t < 128) s_cnt[t] = 0;
  __syncthreads();
  for (int i = t; i < cnt_b; i += 256)
    atomicAdd(&s_cnt[bbuf[b * BCAP + i] >> 16], 1);
  __syncthreads();

  if (t < 128) s_scan[t] = s_cnt[t];
  __syncthreads();
  for (int off = 1; off < 128; off <<= 1) {
    int v = 0;
    if (t < 128 && t >= off) v = s_scan[t - off];
    __syncthreads();
    if (t < 128) s_scan[t] += v;
    __syncthreads();
  }
  if (t < 128) s_cur[t] = s_scan[t] - s_cnt[t];  // exclusive

  const int node = b * NPB + t;
  if (t < NPB && node < NN) {
    int c = s_cnt[t];
    row_start[node] = base + s_scan[t] - c;
    counts[node] = c;
    float di = rsqrtf(1.0f + (float)c);
    dinv[node] = di;
    s_dinv[t] = di;
  }
  __syncthreads();

  for (int i = t; i < cnt_b; i += 256) {
    unsigned w = bbuf[b * BCAP + i];
    int pos = atomicAdd(&s_cur[w >> 16], 1);
    s_sorted[pos] = (unsigned short)(w & 0xFFFFu);
  }
  __syncthreads();
  for (int i = t; i < cnt_b; i += 256) srcs[base + i] = s_sorted[i];

  // ---- degree-sorted perm for this bucket (reads s_cnt, still intact) ----
  const int na = max(0, min(NN - b * NPB, NPB));  // active nodes in bucket
  if (t < 64) d_hist[t] = 0;
  __syncthreads();
  const bool activeN = (t < na);
  const int deg = activeN ? min(s_cnt[t], 63) : 0;
  if (activeN) atomicAdd(&d_hist[deg], 1);
  __syncthreads();
  if (t < 64) d_cur[t] = d_hist[t];
  __syncthreads();
  for (int off = 1; off < 64; off <<= 1) {
    int v = 0;
    if (t < 64 && t >= off) v = d_cur[t - off];
    __syncthreads();
    if (t < 64) d_cur[t] += v;
    __syncthreads();
  }
  if (t < 64) d_cur[t] -= d_hist[t];  // exclusive
  __syncthreads();
  if (activeN) {
    int r = atomicAdd(&d_cur[deg], 1);
    s_permL[r] = t;
  }
  __syncthreads();
  if (t < NPB)
    perm[b * NPB + t] =
        (t < na) ? (unsigned)(b * NPB + s_permL[t]) : 0xFFFFFFFFu;

  // fused: u = fp16(dinv * x), stride 64 halves
  const float4* x4 = (const float4*)x;
  for (int i = t; i < NPB * 16; i += 256) {
    int nl = i >> 4, q = i & 15;
    int n = b * NPB + nl;
    if (n < NN) {
      float di = s_dinv[nl];
      float4 v = x4[(size_t)n * 16 + q];
      __half2 h01 = __floats2half2_rn(v.x * di, v.y * di);
      __half2 h23 = __floats2half2_rn(v.z * di, v.w * di);
      uint2 pk;
      pk.x = *(unsigned*)&h01;
      pk.y = *(unsigned*)&h23;
      *(uint2*)(u + (size_t)n * 64 + 4 * q) = pk;
    }
  }
}

// -------- XCD-sliced, degree-sorted gather: B[n] = A[n] + sum A[src] --------
// CP = padded halves per row (64 or 128). slice = bid&7 owns halves
// [CP/8*s, CP/8*(s+1)); 2 lanes per node (h = t&1). Per-XCD random working
// set = 50K * 64B line = 3.2MB < 4MB L2 (assuming bid%8 -> XCD round-robin;
// correctness is mapping-independent). A fp16, B fp32 (stride CP).
template <int CP>
__global__ __launch_bounds__(256) void gather_slice(
    const unsigned* __restrict__ perm, const int* __restrict__ row_start,
    const int* __restrict__ counts, const unsigned short* __restrict__ srcs,
    const __half* __restrict__ A, float* __restrict__ B) {
  constexpr int HL = CP / 16;  // halves per lane: 8 (CP=128) or 4 (CP=64)
  const int s = blockIdx.x & 7;
  const int i = (blockIdx.x >> 3) * 128 + (threadIdx.x >> 1);
  if (i >= NB * NPB) return;
  const unsigned node = perm[i];
  if (node == 0xFFFFFFFFu) return;
  const int h = threadIdx.x & 1;
  const int vofs = 2 * s + h;  // VT units; row = 16 VT for both CP

  float a[HL];
  const int s0 = row_start[node];
  const int cnt = counts[node];

  if constexpr (CP == 128) {
    const uint4* Ap = (const uint4*)A + vofs;
    {
      uint4 v = Ap[(size_t)node * 16];
      const __half2* hp = (const __half2*)&v;
      #pragma unroll
      for (int k = 0; k < 4; ++k) {
        float2 f = __half22float2(hp[k]);
        a[2 * k] = f.x;
        a[2 * k + 1] = f.y;
      }
    }
    int p = 0;
    for (; p + 4 <= cnt; p += 4) {
      int sa = srcs[s0 + p + 0], sb = srcs[s0 + p + 1];
      int sc = srcs[s0 + p + 2], sd = srcs[s0 + p + 3];
      uint4 va = Ap[(size_t)sa * 16];
      uint4 vb = Ap[(size_t)sb * 16];
      uint4 vc = Ap[(size_t)sc * 16];
      uint4 vd = Ap[(size_t)sd * 16];
      const __half2* ha = (const __half2*)&va;
      const __half2* hb = (const __half2*)&vb;
      const __half2* hc = (const __half2*)&vc;
      const __half2* hd = (const __half2*)&vd;
      #pragma unroll
      for (int k = 0; k < 4; ++k) {
        float2 fa = __half22float2(ha[k]);
        float2 fb = __half22float2(hb[k]);
        float2 fc = __half22float2(hc[k]);
        float2 fd = __half22float2(hd[k]);
        a[2 * k] += (fa.x + fb.x) + (fc.x + fd.x);
        a[2 * k + 1] += (fa.y + fb.y) + (fc.y + fd.y);
      }
    }
    for (; p < cnt; ++p) {
      uint4 v = Ap[(size_t)srcs[s0 + p] * 16];
      const __half2* hp = (const __half2*)&v;
      #pragma unroll
      for (int k = 0; k < 4; ++k) {
        float2 f = __half22float2(hp[k]);
        a[2 * k] += f.x;
        a[2 * k + 1] += f.y;
      }
    }
    float* bp = B + (size_t)node * 128 + 16 * s + 8 * h;
    *(float4*)bp = make_float4(a[0], a[1], a[2], a[3]);
    *(float4*)(bp + 4) = make_float4(a[4], a[5], a[6], a[7]);
  } else {
    const uint2* Ap = (const uint2*)A + vofs;
    {
      uint2 v = Ap[(size_t)node * 16];
      const __half2* hp = (const __half2*)&v;
      #pragma unroll
      for (int k = 0; k < 2; ++k) {
        float2 f = __half22float2(hp[k]);
        a[2 * k] = f.x;
        a[2 * k + 1] = f.y;
      }
    }
    int p = 0;
    for (; p + 4 <= cnt; p += 4) {
      int sa = srcs[s0 + p + 0], sb = srcs[s0 + p + 1];
      int sc = srcs[s0 + p + 2], sd = srcs[s0 + p + 3];
      uint2 va = Ap[(size_t)sa * 16];
      uint2 vb = Ap[(size_t)sb * 16];
      uint2 vc = Ap[(size_t)sc * 16];
      uint2 vd = Ap[(size_t)sd * 16];
      const __half2* ha = (const __half2*)&va;
      const __half2* hb = (const __half2*)&vb;
      const __half2* hc = (const __half2*)&vc;
      const __half2* hd = (const __half2*)&vd;
      #pragma unroll
      for (int k = 0; k < 2; ++k) {
        float2 fa = __half22float2(ha[k]);
        float2 fb = __half22float2(hb[k]);
        float2 fc = __half22float2(hc[k]);
        float2 fd = __half22float2(hd[k]);
        a[2 * k] += (fa.x + fb.x) + (fc.x + fd.x);
        a[2 * k + 1] += (fa.y + fb.y) + (fc.y + fd.y);
      }
    }
    for (; p < cnt; ++p) {
      uint2 v = Ap[(size_t)srcs[s0 + p] * 16];
      const __half2* hp = (const __half2*)&v;
      #pragma unroll
      for (int k = 0; k < 2; ++k) {
        float2 f = __half22float2(hp[k]);
        a[2 * k] += f.x;
        a[2 * k + 1] += f.y;
      }
    }
    float* bp = B + (size_t)node * 64 + 8 * s + 4 * h;
    *(float4*)bp = make_float4(a[0], a[1], a[2], a[3]);
  }
}

// ---------------- SGPR-W row GEMM ----------------
// thread = (node, M-slice of MS). acc in VGPRs; W via wave-uniform s_load.
// EMODE 1: di*relu(di*acc+b)  2: relu(di*acc+b)  3: acc+b
// OH: fp16 output.  LDX/LDO: row strides.  PADO: zero-fill halves [96,128)
// (done by the c0==64 slice) for the padded fp16 consumer.
template <int K, int M, int MS, int EMODE, int OH, int LDX, int LDO, int PADO>
__global__ __launch_bounds__(256) void sgemm(
    const float* __restrict__ X, const float* __restrict__ W,
    const float* __restrict__ bias, const float* __restrict__ dinv,
    void* __restrict__ outv) {
  constexpr int NS = M / MS;
  constexpr int WQ = MS / 4;
  const int bid = blockIdx.x;
  const int chunk = (NS == 1) ? bid : bid / NS;
  const int slice = (NS == 1) ? 0 : bid - chunk * NS;
  const int c0 = slice * MS;
  const int t = threadIdx.x;
  const int nr = chunk * 256 + t;
  const bool act = nr < NN;
  const int n = act ? nr : NN - 1;  // clamp: safe loads, store guarded

  float acc[MS] = {};
  const float4* __restrict__ xr = (const float4*)(X + (size_t)n * LDX);
  #pragma unroll 4
  for (int kq = 0; kq < K / 4; ++kq) {
    float4 xv = xr[kq];
    const float xk[4] = {xv.x, xv.y, xv.z, xv.w};
    #pragma unroll
    for (int c = 0; c < 4; ++c) {
      const float* __restrict__ wrow = W + (size_t)(4 * kq + c) * M + c0;
      #pragma unroll
      for (int j = 0; j < MS; ++j)  // wrow[j] is wave-uniform -> s_load
        acc[j] = fmaf(xk[c], wrow[j], acc[j]);
    }
  }

  if (act) {
    const float di = (EMODE != 3) ? dinv[n] : 0.f;
    #pragma unroll
    for (int j4 = 0; j4 < WQ; ++j4) {
      float b0 = bias[c0 + 4 * j4 + 0], b1 = bias[c0 + 4 * j4 + 1];
      float b2 = bias[c0 + 4 * j4 + 2], b3 = bias[c0 + 4 * j4 + 3];
      float a0 = acc[4 * j4 + 0], a1 = acc[4 * j4 + 1];
      float a2 = acc[4 * j4 + 2], a3 = acc[4 * j4 + 3];
      float4 r;
      if (EMODE == 1) {
        r.x = di * fmaxf(fmaf(di, a0, b0), 0.f);
        r.y = di * fmaxf(fmaf(di, a1, b1), 0.f);
        r.z = di * fmaxf(fmaf(di, a2, b2), 0.f);
        r.w = di * fmaxf(fmaf(di, a3, b3), 0.f);
      } else if (EMODE == 2) {
        r.x = fmaxf(fmaf(di, a0, b0), 0.f);
        r.y = fmaxf(fmaf(di, a1, b1), 0.f);
        r.z = fmaxf(fmaf(di, a2, b2), 0.f);
        r.w = fmaxf(fmaf(di, a3, b3), 0.f);
      } else {
        r.x = a0 + b0; r.y = a1 + b1; r.z = a2 + b2; r.w = a3 + b3;
      }
      if (OH) {
        __half2 h01 = __floats2half2_rn(r.x, r.y);
        __half2 h23 = __floats2half2_rn(r.z, r.w);
        uint2 pk;
        pk.x = *(unsigned*)&h01;
        pk.y = *(unsigned*)&h23;
        *(uint2*)((__half*)outv + (size_t)n * LDO + c0 + 4 * j4) = pk;
      } else {
        *(float4*)((float*)outv + (size_t)n * LDO + c0 + 4 * j4) = r;
      }
    }
    if (OH && PADO && c0 == M - MS) {  // zero halves [96,128)
      uint4 z = {0u, 0u, 0u, 0u};
      __half* oh = (__half*)outv + (size_t)n * LDO + 96;
      *(uint4*)(oh + 0) = z;
      *(uint4*)(oh + 8) = z;
      *(uint4*)(oh + 16) = z;
      *(uint4*)(oh + 24) = z;
    }
  }
}

extern "C" void kernel_launch(void* const* d_in, const int* in_sizes, int n_in,
                              void* d_out, int out_size, void* d_ws,
                              size_t ws_size, hipStream_t stream) {
  const float* x   = (const float*)d_in[0];
  const int*   ei  = (const int*)d_in[1];
  const float* W1  = (const float*)d_in[2];
  const float* b1  = (const float*)d_in[3];
  const float* W2  = (const float*)d_in[4];
  const float* b2  = (const float*)d_in[5];
  const float* Wfc = (const float*)d_in[6];
  const float* bfc = (const float*)d_in[7];
  float* out = (float*)d_out;

  // workspace: lifetime-reused regions
  //   R0 [NN*96 f32]:  u_h (fp16 s64) | g1_h (fp16 s128) | h2 (f32 s96)
  //   R1 [NN*128 f32]: bbuf | B1 (f32 s64) | B2 (f32 s128)
  float* dinv = (float*)d_ws;                        // [50048]
  float* R0 = dinv + 50048;                          // [NN*96]
  float* R1 = R0 + (size_t)NN * 96;                  // [NN*128]
  int* row_start = (int*)(R1 + (size_t)NN * 128);    // [50048]
  int* counts = row_start + 50048;                   // [50048]
  int* bcnt = counts + 50048;                        // [512]
  unsigned short* srcs = (unsigned short*)(bcnt + 512);  // [NE] u16
  unsigned* perm = (unsigned*)(srcs + NE);           // [NB*NPB]
  unsigned* bbuf = (unsigned*)R1;                    // 4MB scratch
  __half* u_h = (__half*)R0;
  __half* g1_h = (__half*)R0;
  float* B1 = R1;
  float* B2 = R1;
  float* h2 = R0;

  zero_bcnt<<<1, 512, 0, stream>>>(bcnt);
  csr_pass1<<<NP1, P1B, 0, stream>>>(ei, bcnt, bbuf);
  csr_pass2<<<NB, 256, 0, stream>>>(bcnt, bbuf, x, row_start, counts, dinv,
                                    u_h, srcs, perm);

  constexpr int CH = (NN + 255) / 256;            // 196 node chunks (sgemm)
  constexpr int GG = (NB * NPB / 128) * 8;        // 392 chunks x 8 slices

  // B1 = gather64(u_h): R0 -> R1
  gather_slice<64><<<GG, 256, 0, stream>>>(perm, row_start, counts, srcs,
                                           u_h, B1);
  // g1_h = fp16pad128(di*relu(di*(B1@W1) + b1)): R1 -> R0
  sgemm<64, 96, 32, 1, 1, 64, 128, 1>
      <<<CH * 3, 256, 0, stream>>>(B1, W1, b1, dinv, g1_h);
  // B2 = gather128(g1_h): R0 -> R1
  gather_slice<128><<<GG, 256, 0, stream>>>(perm, row_start, counts, srcs,
                                            g1_h, B2);
  // h2 = relu(di*(B2@W2) + b2): R1 -> R0
  sgemm<96, 96, 32, 2, 0, 128, 96, 0>
      <<<CH * 3, 256, 0, stream>>>(B2, W2, b2, dinv, h2);
  // out = h2 @ Wfc + bfc
  sgemm<96, 32, 32, 3, 0, 96, 32, 0>
      <<<CH, 256, 0, stream>>>(h2, Wfc, bfc, dinv, out);
}

// Round 10
// 202.166 us; speedup vs baseline: 1.2506x; 1.2506x over previous
//
#include <hip/hip_runtime.h>
#include <hip/hip_fp16.h>

// GCN: N=50000 nodes, E=800000 edges, 64 -> 96 -> 96 -> 32, fp32.
// R9 = R7 (145us baseline) + two fixes:
//  (a) degree-sorted perm ordering in gather (R8's perm, WITHOUT channel
//      slicing - R8's slicing read 32B of each random 64/128B line -> 234MB
//      fills; full-row 192B reads keep line utilization ~100%).
//  (b) sgemm2+FC fused with FULL unroll (R6 failed via partial unroll ->
//      runtime-indexed acc -> scratch; all-static indices keep acc[96]+o[32]
//      in VGPRs). Saves 38MB h2 roundtrip + a dispatch.
// Pipeline:
//   pass1: bucket edges by dst/98; pass2: CSR + dinv + perm + u_h=fp16(di*x)
//   B1 = gather64(u_h,perm);  g1_h = fp16(di*relu(di*(B1@W1)+b1))
//   B2 = gather96(g1_h,perm); out = relu(di*(B2@W2)+b2) @ Wfc + bfc

constexpr int NN = 50000;
constexpr int NE = 800000;
constexpr int NB = 512;     // buckets
constexpr int NPB = 98;     // nodes per bucket (512*98 = 50176 >= NN)
constexpr int BCAP = 2048;  // max edges per bucket (mean 1563; verified fit)
constexpr int EPB = 8192;   // edges per pass1 block
constexpr int P1B = 1024;   // pass1 block size
constexpr int NP1 = (NE + EPB - 1) / EPB;  // 98 blocks

__global__ void zero_bcnt(int* bcnt) {
  int i = threadIdx.x;
  if (i < NB) bcnt[i] = 0;
}

// ---------------- CSR pass 1: block-local sort + bulk reservation ----------
__global__ __launch_bounds__(P1B) void csr_pass1(const int* __restrict__ ei,
                                                 int* __restrict__ bcnt,
                                                 unsigned* __restrict__ bbuf) {
  __shared__ unsigned sorted[EPB];  // 32KB
  __shared__ int hist[NB];
  __shared__ int lofs[NB];
  __shared__ int cursor[NB];
  __shared__ int gbase[NB];
  const int t = threadIdx.x;
  const int e0 = blockIdx.x * EPB;
  const int ecnt = min(EPB, NE - e0);

  for (int i = t; i < NB; i += P1B) hist[i] = 0;
  __syncthreads();

  for (int i = t; i < ecnt; i += P1B) {
    unsigned dst = (unsigned)ei[NE + e0 + i];
    atomicAdd(&hist[dst / NPB], 1);
  }
  __syncthreads();

  if (t < NB) lofs[t] = hist[t];
  __syncthreads();
  for (int off = 1; off < NB; off <<= 1) {
    int v = 0;
    if (t < NB && t >= off) v = lofs[t - off];
    __syncthreads();
    if (t < NB) lofs[t] += v;
    __syncthreads();
  }
  if (t < NB) {
    int ex = lofs[t] - hist[t];  // exclusive
    lofs[t] = ex;
    cursor[t] = ex;
    gbase[t] = atomicAdd(&bcnt[t], hist[t]);
  }
  __syncthreads();

  for (int i = t; i < ecnt; i += P1B) {
    unsigned src = (unsigned)ei[e0 + i];
    unsigned dst = (unsigned)ei[NE + e0 + i];
    unsigned b = dst / NPB;
    unsigned dl = dst - b * NPB;
    int pos = atomicAdd(&cursor[b], 1);
    sorted[pos] = (b << 23) | (dl << 16) | src;
  }
  __syncthreads();

  for (int i = t; i < ecnt; i += P1B) {
    unsigned pw = sorted[i];
    unsigned b = pw >> 23;
    int off_in_b = gbase[b] + (i - lofs[b]);
    if (off_in_b < BCAP)
      bbuf[b * BCAP + off_in_b] = pw & 0x007FFFFFu;  // (dl<<16)|src
  }
}

// ------- CSR pass 2: per-bucket LDS sort + CSR + degree-sorted perm -------
__global__ __launch_bounds__(256) void csr_pass2(
    const int* __restrict__ bcnt, const unsigned* __restrict__ bbuf,
    const float* __restrict__ x, int* __restrict__ row_start,
    int* __restrict__ counts, float* __restrict__ dinv,
    __half* __restrict__ u, unsigned short* __restrict__ srcs,
    unsigned* __restrict__ perm) {
  __shared__ int s_red[256];
  __shared__ int s_cnt[128];
  __shared__ int s_scan[128];
  __shared__ int s_cur[128];
  __shared__ float s_dinv[128];
  __shared__ unsigned short s_sorted[BCAP];
  __shared__ int d_hist[64];
  __shared__ int d_cur[64];
  __shared__ int s_permL[NPB];
  const int b = blockIdx.x, t = threadIdx.x;
  const int cnt_b = min(bcnt[b], BCAP);

  int acc = 0;
  for (int j = t; j < b; j += 256) acc += min(bcnt[j], BCAP);
  s_red[t] = acc;
  __syncthreads();
  for (int off = 128; off > 0; off >>= 1) {
    if (t < off) s_red[t] += s_red[t + off];
    __syncthreads();
  }
  const int base = s_red[0];

  if (t < 128) s_cnt[t] = 0;
  __syncthreads();
  for (int i = t; i < cnt_b; i += 256)
    atomicAdd(&s_cnt[bbuf[b * BCAP + i] >> 16], 1);
  __syncthreads();

  if (t < 128) s_scan[t] = s_cnt[t];
  __syncthreads();
  for (int off = 1; off < 128; off <<= 1) {
    int v = 0;
    if (t < 128 && t >= off) v = s_scan[t - off];
    __syncthreads();
    if (t < 128) s_scan[t] += v;
    __syncthreads();
  }
  if (t < 128) s_cur[t] = s_scan[t] - s_cnt[t];  // exclusive

  const int node = b * NPB + t;
  if (t < NPB && node < NN) {
    int c = s_cnt[t];
    row_start[node] = base + s_scan[t] - c;
    counts[node] = c;
    float di = rsqrtf(1.0f + (float)c);
    dinv[node] = di;
    s_dinv[t] = di;
  }
  __syncthreads();

  for (int i = t; i < cnt_b; i += 256) {
    unsigned w = bbuf[b * BCAP + i];
    int pos = atomicAdd(&s_cur[w >> 16], 1);
    s_sorted[pos] = (unsigned short)(w & 0xFFFFu);
  }
  __syncthreads();
  for (int i = t; i < cnt_b; i += 256) srcs[base + i] = s_sorted[i];

  // ---- degree-sorted perm for this bucket (s_cnt intact) ----
  const int na = max(0, min(NN - b * NPB, NPB));  // active nodes in bucket
  if (t < 64) d_hist[t] = 0;
  __syncthreads();
  const bool activeN = (t < na);
  const int deg = activeN ? min(s_cnt[t], 63) : 0;
  if (activeN) atomicAdd(&d_hist[deg], 1);
  __syncthreads();
  if (t < 64) d_cur[t] = d_hist[t];
  __syncthreads();
  for (int off = 1; off < 64; off <<= 1) {
    int v = 0;
    if (t < 64 && t >= off) v = d_cur[t - off];
    __syncthreads();
    if (t < 64) d_cur[t] += v;
    __syncthreads();
  }
  if (t < 64) d_cur[t] -= d_hist[t];  // exclusive
  __syncthreads();
  if (activeN) {
    int r = atomicAdd(&d_cur[deg], 1);
    s_permL[r] = t;
  }
  __syncthreads();
  if (t < NPB)
    perm[b * NPB + t] =
        (t < na) ? (unsigned)(b * NPB + s_permL[t]) : 0xFFFFFFFFu;

  // fused: u = fp16(dinv * x), stride 64 halves
  const float4* x4 = (const float4*)x;
  for (int i = t; i < NPB * 16; i += 256) {
    int nl = i >> 4, q = i & 15;
    int n = b * NPB + nl;
    if (n < NN) {
      float di = s_dinv[nl];
      float4 v = x4[(size_t)n * 16 + q];
      __half2 h01 = __floats2half2_rn(v.x * di, v.y * di);
      __half2 h23 = __floats2half2_rn(v.z * di, v.w * di);
      uint2 pk;
      pk.x = *(unsigned*)&h01;
      pk.y = *(unsigned*)&h23;
      *(uint2*)(u + (size_t)n * 64 + 4 * q) = pk;
    }
  }
}

// ------- perm-ordered gather: B[n] = A[n] + sum_{s in adj(n)} A[s] -------
// A fp16 full rows (16B/lane contiguous, line-friendly); B fp32 sequential.
// Nodes processed in degree-sorted perm order -> uniform loop length per wave.
template <int C>
__global__ __launch_bounds__(256) void gather_h(
    const unsigned* __restrict__ perm, const int* __restrict__ row_start,
    const int* __restrict__ counts, const unsigned short* __restrict__ srcs,
    const __half* __restrict__ A, float* __restrict__ B) {
  constexpr int QP = C / 8;  // 16B chunks per row: 12 (96ch) or 8 (64ch)
  int gid = blockIdx.x * blockDim.x + threadIdx.x;
  if (gid >= NB * NPB * QP) return;
  int i, q;
  if constexpr ((QP & (QP - 1)) == 0) {
    i = gid >> 3;  // QP == 8
    q = gid & 7;
  } else {
    i = gid / QP;
    q = gid - i * QP;
  }
  const unsigned node = perm[i];
  if (node == 0xFFFFFFFFu) return;
  const int n = (int)node;
  const uint4* A4 = (const uint4*)A + q;  // row = QP uint4 (8 halves each)

  float a[8] = {};
  {  // self-loop term
    uint4 v = A4[(size_t)n * QP];
    const __half2* h = (const __half2*)&v;
    #pragma unroll
    for (int k = 0; k < 4; ++k) {
      float2 f = __half22float2(h[k]);
      a[2 * k] = f.x;
      a[2 * k + 1] = f.y;
    }
  }
  const int s0 = row_start[n];
  const int cnt = counts[n];
  int p = 0;
  for (; p + 4 <= cnt; p += 4) {  // 4 independent loads in flight
    int sa = srcs[s0 + p + 0];
    int sb = srcs[s0 + p + 1];
    int sc = srcs[s0 + p + 2];
    int sd = srcs[s0 + p + 3];
    uint4 va = A4[(size_t)sa * QP];
    uint4 vb = A4[(size_t)sb * QP];
    uint4 vc = A4[(size_t)sc * QP];
    uint4 vd = A4[(size_t)sd * QP];
    const __half2* ha = (const __half2*)&va;
    const __half2* hb = (const __half2*)&vb;
    const __half2* hc = (const __half2*)&vc;
    const __half2* hd = (const __half2*)&vd;
    #pragma unroll
    for (int k = 0; k < 4; ++k) {
      float2 fa = __half22float2(ha[k]);
      float2 fb = __half22float2(hb[k]);
      float2 fc = __half22float2(hc[k]);
      float2 fd = __half22float2(hd[k]);
      a[2 * k] += (fa.x + fb.x) + (fc.x + fd.x);
      a[2 * k + 1] += (fa.y + fb.y) + (fc.y + fd.y);
    }
  }
  for (; p < cnt; ++p) {
    int s = srcs[s0 + p];
    uint4 v = A4[(size_t)s * QP];
    const __half2* h = (const __half2*)&v;
    #pragma unroll
    for (int k = 0; k < 4; ++k) {
      float2 f = __half22float2(h[k]);
      a[2 * k] += f.x;
      a[2 * k + 1] += f.y;
    }
  }
  float* bp = B + (size_t)n * C + 8 * q;
  *(float4*)bp = make_float4(a[0], a[1], a[2], a[3]);
  *(float4*)(bp + 4) = make_float4(a[4], a[5], a[6], a[7]);
}

// ---------------- SGPR-W row GEMM (layer 1) ----------------
// EMODE 1: out = di*relu(di*acc + b); OH: fp16 output.
template <int K, int M, int MS, int EMODE, int OH>
__global__ __launch_bounds__(256) void sgemm(
    const float* __restrict__ X, const float* __restrict__ W,
    const float* __restrict__ bias, const float* __restrict__ dinv,
    void* __restrict__ outv) {
  constexpr int NS = M / MS;
  constexpr int WQ = MS / 4;
  const int bid = blockIdx.x;
  const int chunk = (NS == 1) ? bid : bid / NS;
  const int slice = (NS == 1) ? 0 : bid - chunk * NS;
  const int c0 = slice * MS;
  const int t = threadIdx.x;
  const int nr = chunk * 256 + t;
  const bool act = nr < NN;
  const int n = act ? nr : NN - 1;  // clamp: safe loads, store guarded

  float acc[MS] = {};
  const float4* __restrict__ xr = (const float4*)(X + (size_t)n * K);
  #pragma unroll 4
  for (int kq = 0; kq < K / 4; ++kq) {
    float4 xv = xr[kq];
    const float xk[4] = {xv.x, xv.y, xv.z, xv.w};
    #pragma unroll
    for (int c = 0; c < 4; ++c) {
      const float* __restrict__ wrow = W + (size_t)(4 * kq + c) * M + c0;
      #pragma unroll
      for (int j = 0; j < MS; ++j)  // wrow[j] is wave-uniform -> s_load
        acc[j] = fmaf(xk[c], wrow[j], acc[j]);
    }
  }

  if (act) {
    const float di = (EMODE != 3) ? dinv[n] : 0.f;
    #pragma unroll
    for (int j4 = 0; j4 < WQ; ++j4) {
      float b0 = bias[c0 + 4 * j4 + 0], b1 = bias[c0 + 4 * j4 + 1];
      float b2 = bias[c0 + 4 * j4 + 2], b3 = bias[c0 + 4 * j4 + 3];
      float a0 = acc[4 * j4 + 0], a1 = acc[4 * j4 + 1];
      float a2 = acc[4 * j4 + 2], a3 = acc[4 * j4 + 3];
      float4 r;
      if (EMODE == 1) {
        r.x = di * fmaxf(fmaf(di, a0, b0), 0.f);
        r.y = di * fmaxf(fmaf(di, a1, b1), 0.f);
        r.z = di * fmaxf(fmaf(di, a2, b2), 0.f);
        r.w = di * fmaxf(fmaf(di, a3, b3), 0.f);
      } else if (EMODE == 2) {
        r.x = fmaxf(fmaf(di, a0, b0), 0.f);
        r.y = fmaxf(fmaf(di, a1, b1), 0.f);
        r.z = fmaxf(fmaf(di, a2, b2), 0.f);
        r.w = fmaxf(fmaf(di, a3, b3), 0.f);
      } else {
        r.x = a0 + b0; r.y = a1 + b1; r.z = a2 + b2; r.w = a3 + b3;
      }
      if (OH) {
        __half2 h01 = __floats2half2_rn(r.x, r.y);
        __half2 h23 = __floats2half2_rn(r.z, r.w);
        uint2 pk;
        pk.x = *(unsigned*)&h01;
        pk.y = *(unsigned*)&h23;
        *(uint2*)((__half*)outv + (size_t)n * M + c0 + 4 * j4) = pk;
      } else {
        *(float4*)((float*)outv + (size_t)n * M + c0 + 4 * j4) = r;
      }
    }
  }
}

// ---------- fused layer-2 GEMM + FC, FULLY unrolled (no runtime idx) -------
// out = relu(di*(X@W2)+b2) @ Wfc + bfc.  acc[96]+o[32] in VGPRs.
__global__ __launch_bounds__(256) void sgemm2fc(
    const float* __restrict__ X, const float* __restrict__ W2,
    const float* __restrict__ b2, const float* __restrict__ Wfc,
    const float* __restrict__ bfc, const float* __restrict__ dinv,
    float* __restrict__ out) {
  const int nr = blockIdx.x * 256 + threadIdx.x;
  const bool act = nr < NN;
  const int n = act ? nr : NN - 1;

  float acc[96];
  #pragma unroll
  for (int j = 0; j < 96; ++j) acc[j] = 0.f;

  const float4* __restrict__ xr = (const float4*)(X + (size_t)n * 96);
  #pragma unroll
  for (int kq = 0; kq < 24; ++kq) {
    float4 xv = xr[kq];
    const float xk0 = xv.x, xk1 = xv.y, xk2 = xv.z, xk3 = xv.w;
    const float* __restrict__ w0 = W2 + (size_t)(4 * kq + 0) * 96;
    const float* __restrict__ w1 = W2 + (size_t)(4 * kq + 1) * 96;
    const float* __restrict__ w2 = W2 + (size_t)(4 * kq + 2) * 96;
    const float* __restrict__ w3 = W2 + (size_t)(4 * kq + 3) * 96;
    #pragma unroll
    for (int j = 0; j < 96; ++j) {
      float a = acc[j];
      a = fmaf(xk0, w0[j], a);
      a = fmaf(xk1, w1[j], a);
      a = fmaf(xk2, w2[j], a);
      a = fmaf(xk3, w3[j], a);
      acc[j] = a;
    }
  }

  const float di = dinv[n];
  float o[32];
  #pragma unroll
  for (int m = 0; m < 32; ++m) o[m] = 0.f;
  #pragma unroll
  for (int k = 0; k < 96; ++k) {
    const float hk = fmaxf(fmaf(di, acc[k], b2[k]), 0.f);
    const float* __restrict__ wrow = Wfc + (size_t)k * 32;
    #pragma unroll
    for (int m = 0; m < 32; ++m) o[m] = fmaf(hk, wrow[m], o[m]);
  }

  if (act) {
    float* op = out + (size_t)n * 32;
    #pragma unroll
    for (int m4 = 0; m4 < 8; ++m4) {
      float4 r;
      r.x = o[4 * m4 + 0] + bfc[4 * m4 + 0];
      r.y = o[4 * m4 + 1] + bfc[4 * m4 + 1];
      r.z = o[4 * m4 + 2] + bfc[4 * m4 + 2];
      r.w = o[4 * m4 + 3] + bfc[4 * m4 + 3];
      *(float4*)(op + 4 * m4) = r;
    }
  }
}

extern "C" void kernel_launch(void* const* d_in, const int* in_sizes, int n_in,
                              void* d_out, int out_size, void* d_ws,
                              size_t ws_size, hipStream_t stream) {
  const float* x   = (const float*)d_in[0];
  const int*   ei  = (const int*)d_in[1];
  const float* W1  = (const float*)d_in[2];
  const float* b1  = (const float*)d_in[3];
  const float* W2  = (const float*)d_in[4];
  const float* b2  = (const float*)d_in[5];
  const float* Wfc = (const float*)d_in[6];
  const float* bfc = (const float*)d_in[7];
  float* out = (float*)d_out;

  // workspace: lifetime-reused regions
  //   R0 [NN*96 f32]: u_h (fp16 s64) | g1_h (fp16 s96)
  //   R1 [NN*96 f32]: bbuf | B1 (f32 s64) | B2 (f32 s96)
  float* dinv = (float*)d_ws;                        // [50048]
  float* R0 = dinv + 50048;                          // [NN*96]
  float* R1 = R0 + (size_t)NN * 96;                  // [NN*96]
  int* row_start = (int*)(R1 + (size_t)NN * 96);     // [50048]
  int* counts = row_start + 50048;                   // [50048]
  int* bcnt = counts + 50048;                        // [512]
  unsigned short* srcs = (unsigned short*)(bcnt + 512);  // [NE] u16
  unsigned* perm = (unsigned*)(srcs + NE);           // [NB*NPB]
  unsigned* bbuf = (unsigned*)R1;                    // 4MB scratch
  __half* u_h = (__half*)R0;
  __half* g1_h = (__half*)R0;
  float* B1 = R1;
  float* B2 = R1;

  zero_bcnt<<<1, 512, 0, stream>>>(bcnt);
  csr_pass1<<<NP1, P1B, 0, stream>>>(ei, bcnt, bbuf);
  csr_pass2<<<NB, 256, 0, stream>>>(bcnt, bbuf, x, row_start, counts, dinv,
                                    u_h, srcs, perm);

  constexpr int CH = (NN + 255) / 256;  // 196 node chunks

  // B1 = gather64(u_h, perm): R0 -> R1
  gather_h<64><<<(NB * NPB * 8 + 255) / 256, 256, 0, stream>>>(
      perm, row_start, counts, srcs, u_h, B1);
  // g1_h = fp16(di*relu(di*(B1@W1) + b1)): R1 -> R0
  sgemm<64, 96, 32, 1, 1><<<CH * 3, 256, 0, stream>>>(B1, W1, b1, dinv, g1_h);
  // B2 = gather96(g1_h, perm): R0 -> R1
  gather_h<96><<<(NB * NPB * 12 + 255) / 256, 256, 0, stream>>>(
      perm, row_start, counts, srcs, g1_h, B2);
  // out = relu(di*(B2@W2)+b2) @ Wfc + bfc: R1 -> out
  sgemm2fc<<<CH, 256, 0, stream>>>(B2, W2, b2, Wfc, bfc, dinv, out);
}

// Round 11
// 135.345 us; speedup vs baseline: 1.8680x; 1.4937x over previous
//
#include <hip/hip_runtime.h>
#include <hip/hip_fp16.h>

// GCN: N=50000 nodes, E=800000 edges, 64 -> 96 -> 96 -> 32, fp32.
// R10: revert R9's sgemm2fc fusion (NOT a spill - a parallelism cliff:
// 50000 threads = 0.77 waves/SIMD on 1024 SIMDs, s_load latency exposed,
// 131-158us). Keep R9's perm-ordered gathers (worked: non-fused budget
// 115->60us). Split sgemms with more M-slices for occupancy: sgemm1 MS=32,
// sgemm2 MS=24 (4 slices, 3.1 waves/SIMD), FC MS=16 (2 slices).
// Pipeline:
//   pass1: bucket edges by dst/98; pass2: CSR + dinv + perm + u_h=fp16(di*x)
//   B1 = gather64(u_h,perm);  g1_h = fp16(di*relu(di*(B1@W1)+b1))
//   B2 = gather96(g1_h,perm); h2 = relu(di*(B2@W2)+b2); out = h2@Wfc+bfc

constexpr int NN = 50000;
constexpr int NE = 800000;
constexpr int NB = 512;     // buckets
constexpr int NPB = 98;     // nodes per bucket (512*98 = 50176 >= NN)
constexpr int BCAP = 2048;  // max edges per bucket (mean 1563; verified fit)
constexpr int EPB = 8192;   // edges per pass1 block
constexpr int P1B = 1024;   // pass1 block size
constexpr int NP1 = (NE + EPB - 1) / EPB;  // 98 blocks

__global__ void zero_bcnt(int* bcnt) {
  int i = threadIdx.x;
  if (i < NB) bcnt[i] = 0;
}

// ---------------- CSR pass 1: block-local sort + bulk reservation ----------
__global__ __launch_bounds__(P1B) void csr_pass1(const int* __restrict__ ei,
                                                 int* __restrict__ bcnt,
                                                 unsigned* __restrict__ bbuf) {
  __shared__ unsigned sorted[EPB];  // 32KB
  __shared__ int hist[NB];
  __shared__ int lofs[NB];
  __shared__ int cursor[NB];
  __shared__ int gbase[NB];
  const int t = threadIdx.x;
  const int e0 = blockIdx.x * EPB;
  const int ecnt = min(EPB, NE - e0);

  for (int i = t; i < NB; i += P1B) hist[i] = 0;
  __syncthreads();

  for (int i = t; i < ecnt; i += P1B) {
    unsigned dst = (unsigned)ei[NE + e0 + i];
    atomicAdd(&hist[dst / NPB], 1);
  }
  __syncthreads();

  if (t < NB) lofs[t] = hist[t];
  __syncthreads();
  for (int off = 1; off < NB; off <<= 1) {
    int v = 0;
    if (t < NB && t >= off) v = lofs[t - off];
    __syncthreads();
    if (t < NB) lofs[t] += v;
    __syncthreads();
  }
  if (t < NB) {
    int ex = lofs[t] - hist[t];  // exclusive
    lofs[t] = ex;
    cursor[t] = ex;
    gbase[t] = atomicAdd(&bcnt[t], hist[t]);
  }
  __syncthreads();

  for (int i = t; i < ecnt; i += P1B) {
    unsigned src = (unsigned)ei[e0 + i];
    unsigned dst = (unsigned)ei[NE + e0 + i];
    unsigned b = dst / NPB;
    unsigned dl = dst - b * NPB;
    int pos = atomicAdd(&cursor[b], 1);
    sorted[pos] = (b << 23) | (dl << 16) | src;
  }
  __syncthreads();

  for (int i = t; i < ecnt; i += P1B) {
    unsigned pw = sorted[i];
    unsigned b = pw >> 23;
    int off_in_b = gbase[b] + (i - lofs[b]);
    if (off_in_b < BCAP)
      bbuf[b * BCAP + off_in_b] = pw & 0x007FFFFFu;  // (dl<<16)|src
  }
}

// ------- CSR pass 2: per-bucket LDS sort + CSR + degree-sorted perm -------
__global__ __launch_bounds__(256) void csr_pass2(
    const int* __restrict__ bcnt, const unsigned* __restrict__ bbuf,
    const float* __restrict__ x, int* __restrict__ row_start,
    int* __restrict__ counts, float* __restrict__ dinv,
    __half* __restrict__ u, unsigned short* __restrict__ srcs,
    unsigned* __restrict__ perm) {
  __shared__ int s_red[256];
  __shared__ int s_cnt[128];
  __shared__ int s_scan[128];
  __shared__ int s_cur[128];
  __shared__ float s_dinv[128];
  __shared__ unsigned short s_sorted[BCAP];
  __shared__ int d_hist[64];
  __shared__ int d_cur[64];
  __shared__ int s_permL[NPB];
  const int b = blockIdx.x, t = threadIdx.x;
  const int cnt_b = min(bcnt[b], BCAP);

  int acc = 0;
  for (int j = t; j < b; j += 256) acc += min(bcnt[j], BCAP);
  s_red[t] = acc;
  __syncthreads();
  for (int off = 128; off > 0; off >>= 1) {
    if (t < off) s_red[t] += s_red[t + off];
    __syncthreads();
  }
  const int base = s_red[0];

  if (t < 128) s_cnt[t] = 0;
  __syncthreads();
  for (int i = t; i < cnt_b; i += 256)
    atomicAdd(&s_cnt[bbuf[b * BCAP + i] >> 16], 1);
  __syncthreads();

  if (t < 128) s_scan[t] = s_cnt[t];
  __syncthreads();
  for (int off = 1; off < 128; off <<= 1) {
    int v = 0;
    if (t < 128 && t >= off) v = s_scan[t - off];
    __syncthreads();
    if (t < 128) s_scan[t] += v;
    __syncthreads();
  }
  if (t < 128) s_cur[t] = s_scan[t] - s_cnt[t];  // exclusive

  const int node = b * NPB + t;
  if (t < NPB && node < NN) {
    int c = s_cnt[t];
    row_start[node] = base + s_scan[t] - c;
    counts[node] = c;
    float di = rsqrtf(1.0f + (float)c);
    dinv[node] = di;
    s_dinv[t] = di;
  }
  __syncthreads();

  for (int i = t; i < cnt_b; i += 256) {
    unsigned w = bbuf[b * BCAP + i];
    int pos = atomicAdd(&s_cur[w >> 16], 1);
    s_sorted[pos] = (unsigned short)(w & 0xFFFFu);
  }
  __syncthreads();
  for (int i = t; i < cnt_b; i += 256) srcs[base + i] = s_sorted[i];

  // ---- degree-sorted perm for this bucket (s_cnt intact) ----
  const int na = max(0, min(NN - b * NPB, NPB));  // active nodes in bucket
  if (t < 64) d_hist[t] = 0;
  __syncthreads();
  const bool activeN = (t < na);
  const int deg = activeN ? min(s_cnt[t], 63) : 0;
  if (activeN) atomicAdd(&d_hist[deg], 1);
  __syncthreads();
  if (t < 64) d_cur[t] = d_hist[t];
  __syncthreads();
  for (int off = 1; off < 64; off <<= 1) {
    int v = 0;
    if (t < 64 && t >= off) v = d_cur[t - off];
    __syncthreads();
    if (t < 64) d_cur[t] += v;
    __syncthreads();
  }
  if (t < 64) d_cur[t] -= d_hist[t];  // exclusive
  __syncthreads();
  if (activeN) {
    int r = atomicAdd(&d_cur[deg], 1);
    s_permL[r] = t;
  }
  __syncthreads();
  if (t < NPB)
    perm[b * NPB + t] =
        (t < na) ? (unsigned)(b * NPB + s_permL[t]) : 0xFFFFFFFFu;

  // fused: u = fp16(dinv * x), stride 64 halves
  const float4* x4 = (const float4*)x;
  for (int i = t; i < NPB * 16; i += 256) {
    int nl = i >> 4, q = i & 15;
    int n = b * NPB + nl;
    if (n < NN) {
      float di = s_dinv[nl];
      float4 v = x4[(size_t)n * 16 + q];
      __half2 h01 = __floats2half2_rn(v.x * di, v.y * di);
      __half2 h23 = __floats2half2_rn(v.z * di, v.w * di);
      uint2 pk;
      pk.x = *(unsigned*)&h01;
      pk.y = *(unsigned*)&h23;
      *(uint2*)(u + (size_t)n * 64 + 4 * q) = pk;
    }
  }
}

// ------- perm-ordered gather: B[n] = A[n] + sum_{s in adj(n)} A[s] -------
// A fp16 full rows (16B/lane contiguous, line-friendly); B fp32 sequential.
// Nodes processed in degree-sorted perm order -> uniform loop length per wave.
template <int C>
__global__ __launch_bounds__(256) void gather_h(
    const unsigned* __restrict__ perm, const int* __restrict__ row_start,
    const int* __restrict__ counts, const unsigned short* __restrict__ srcs,
    const __half* __restrict__ A, float* __restrict__ B) {
  constexpr int QP = C / 8;  // 16B chunks per row: 12 (96ch) or 8 (64ch)
  int gid = blockIdx.x * blockDim.x + threadIdx.x;
  if (gid >= NB * NPB * QP) return;
  int i, q;
  if constexpr ((QP & (QP - 1)) == 0) {
    i = gid >> 3;  // QP == 8
    q = gid & 7;
  } else {
    i = gid / QP;
    q = gid - i * QP;
  }
  const unsigned node = perm[i];
  if (node == 0xFFFFFFFFu) return;
  const int n = (int)node;
  const uint4* A4 = (const uint4*)A + q;  // row = QP uint4 (8 halves each)

  float a[8] = {};
  {  // self-loop term
    uint4 v = A4[(size_t)n * QP];
    const __half2* h = (const __half2*)&v;
    #pragma unroll
    for (int k = 0; k < 4; ++k) {
      float2 f = __half22float2(h[k]);
      a[2 * k] = f.x;
      a[2 * k + 1] = f.y;
    }
  }
  const int s0 = row_start[n];
  const int cnt = counts[n];
  int p = 0;
  for (; p + 4 <= cnt; p += 4) {  // 4 independent loads in flight
    int sa = srcs[s0 + p + 0];
    int sb = srcs[s0 + p + 1];
    int sc = srcs[s0 + p + 2];
    int sd = srcs[s0 + p + 3];
    uint4 va = A4[(size_t)sa * QP];
    uint4 vb = A4[(size_t)sb * QP];
    uint4 vc = A4[(size_t)sc * QP];
    uint4 vd = A4[(size_t)sd * QP];
    const __half2* ha = (const __half2*)&va;
    const __half2* hb = (const __half2*)&vb;
    const __half2* hc = (const __half2*)&vc;
    const __half2* hd = (const __half2*)&vd;
    #pragma unroll
    for (int k = 0; k < 4; ++k) {
      float2 fa = __half22float2(ha[k]);
      float2 fb = __half22float2(hb[k]);
      float2 fc = __half22float2(hc[k]);
      float2 fd = __half22float2(hd[k]);
      a[2 * k] += (fa.x + fb.x) + (fc.x + fd.x);
      a[2 * k + 1] += (fa.y + fb.y) + (fc.y + fd.y);
    }
  }
  for (; p < cnt; ++p) {
    int s = srcs[s0 + p];
    uint4 v = A4[(size_t)s * QP];
    const __half2* h = (const __half2*)&v;
    #pragma unroll
    for (int k = 0; k < 4; ++k) {
      float2 f = __half22float2(h[k]);
      a[2 * k] += f.x;
      a[2 * k + 1] += f.y;
    }
  }
  float* bp = B + (size_t)n * C + 8 * q;
  *(float4*)bp = make_float4(a[0], a[1], a[2], a[3]);
  *(float4*)(bp + 4) = make_float4(a[4], a[5], a[6], a[7]);
}

// ---------------- SGPR-W row GEMM ----------------
// thread = (node, M-slice of MS). acc in VGPRs; W via wave-uniform s_load.
// EMODE 1: di*relu(di*acc+b)  2: relu(di*acc+b)  3: acc+b.  OH: fp16 out.
template <int K, int M, int MS, int EMODE, int OH>
__global__ __launch_bounds__(256) void sgemm(
    const float* __restrict__ X, const float* __restrict__ W,
    const float* __restrict__ bias, const float* __restrict__ dinv,
    void* __restrict__ outv) {
  constexpr int NS = M / MS;
  constexpr int WQ = MS / 4;
  const int bid = blockIdx.x;
  const int chunk = (NS == 1) ? bid : bid / NS;
  const int slice = (NS == 1) ? 0 : bid - chunk * NS;
  const int c0 = slice * MS;
  const int t = threadIdx.x;
  const int nr = chunk * 256 + t;
  const bool act = nr < NN;
  const int n = act ? nr : NN - 1;  // clamp: safe loads, store guarded

  float acc[MS] = {};
  const float4* __restrict__ xr = (const float4*)(X + (size_t)n * K);
  #pragma unroll 4
  for (int kq = 0; kq < K / 4; ++kq) {
    float4 xv = xr[kq];
    const float xk[4] = {xv.x, xv.y, xv.z, xv.w};
    #pragma unroll
    for (int c = 0; c < 4; ++c) {
      const float* __restrict__ wrow = W + (size_t)(4 * kq + c) * M + c0;
      #pragma unroll
      for (int j = 0; j < MS; ++j)  // wrow[j] is wave-uniform -> s_load
        acc[j] = fmaf(xk[c], wrow[j], acc[j]);
    }
  }

  if (act) {
    const float di = (EMODE != 3) ? dinv[n] : 0.f;
    #pragma unroll
    for (int j4 = 0; j4 < WQ; ++j4) {
      float b0 = bias[c0 + 4 * j4 + 0], b1 = bias[c0 + 4 * j4 + 1];
      float b2 = bias[c0 + 4 * j4 + 2], b3 = bias[c0 + 4 * j4 + 3];
      float a0 = acc[4 * j4 + 0], a1 = acc[4 * j4 + 1];
      float a2 = acc[4 * j4 + 2], a3 = acc[4 * j4 + 3];
      float4 r;
      if (EMODE == 1) {
        r.x = di * fmaxf(fmaf(di, a0, b0), 0.f);
        r.y = di * fmaxf(fmaf(di, a1, b1), 0.f);
        r.z = di * fmaxf(fmaf(di, a2, b2), 0.f);
        r.w = di * fmaxf(fmaf(di, a3, b3), 0.f);
      } else if (EMODE == 2) {
        r.x = fmaxf(fmaf(di, a0, b0), 0.f);
        r.y = fmaxf(fmaf(di, a1, b1), 0.f);
        r.z = fmaxf(fmaf(di, a2, b2), 0.f);
        r.w = fmaxf(fmaf(di, a3, b3), 0.f);
      } else {
        r.x = a0 + b0; r.y = a1 + b1; r.z = a2 + b2; r.w = a3 + b3;
      }
      if (OH) {
        __half2 h01 = __floats2half2_rn(r.x, r.y);
        __half2 h23 = __floats2half2_rn(r.z, r.w);
        uint2 pk;
        pk.x = *(unsigned*)&h01;
        pk.y = *(unsigned*)&h23;
        *(uint2*)((__half*)outv + (size_t)n * M + c0 + 4 * j4) = pk;
      } else {
        *(float4*)((float*)outv + (size_t)n * M + c0 + 4 * j4) = r;
      }
    }
  }
}

extern "C" void kernel_launch(void* const* d_in, const int* in_sizes, int n_in,
                              void* d_out, int out_size, void* d_ws,
                              size_t ws_size, hipStream_t stream) {
  const float* x   = (const float*)d_in[0];
  const int*   ei  = (const int*)d_in[1];
  const float* W1  = (const float*)d_in[2];
  const float* b1  = (const float*)d_in[3];
  const float* W2  = (const float*)d_in[4];
  const float* b2  = (const float*)d_in[5];
  const float* Wfc = (const float*)d_in[6];
  const float* bfc = (const float*)d_in[7];
  float* out = (float*)d_out;

  // workspace: lifetime-reused regions
  //   R0 [NN*96 f32]: u_h (fp16 s64) | g1_h (fp16 s96) | h2 (f32 s96)
  //   R1 [NN*96 f32]: bbuf | B1 (f32 s64) | B2 (f32 s96)
  float* dinv = (float*)d_ws;                        // [50048]
  float* R0 = dinv + 50048;                          // [NN*96]
  float* R1 = R0 + (size_t)NN * 96;                  // [NN*96]
  int* row_start = (int*)(R1 + (size_t)NN * 96);     // [50048]
  int* counts = row_start + 50048;                   // [50048]
  int* bcnt = counts + 50048;                        // [512]
  unsigned short* srcs = (unsigned short*)(bcnt + 512);  // [NE] u16
  unsigned* perm = (unsigned*)(srcs + NE);           // [NB*NPB]
  unsigned* bbuf = (unsigned*)R1;                    // 4MB scratch
  __half* u_h = (__half*)R0;
  __half* g1_h = (__half*)R0;
  float* B1 = R1;
  float* B2 = R1;
  float* h2 = R0;

  zero_bcnt<<<1, 512, 0, stream>>>(bcnt);
  csr_pass1<<<NP1, P1B, 0, stream>>>(ei, bcnt, bbuf);
  csr_pass2<<<NB, 256, 0, stream>>>(bcnt, bbuf, x, row_start, counts, dinv,
                                    u_h, srcs, perm);

  constexpr int CH = (NN + 255) / 256;  // 196 node chunks

  // B1 = gather64(u_h, perm): R0 -> R1
  gather_h<64><<<(NB * NPB * 8 + 255) / 256, 256, 0, stream>>>(
      perm, row_start, counts, srcs, u_h, B1);
  // g1_h = fp16(di*relu(di*(B1@W1) + b1)): R1 -> R0
  sgemm<64, 96, 32, 1, 1><<<CH * 3, 256, 0, stream>>>(B1, W1, b1, dinv, g1_h);
  // B2 = gather96(g1_h, perm): R0 -> R1
  gather_h<96><<<(NB * NPB * 12 + 255) / 256, 256, 0, stream>>>(
      perm, row_start, counts, srcs, g1_h, B2);
  // h2 = relu(di*(B2@W2) + b2): R1 -> R0  (MS=24: 4 slices, 3.1 waves/SIMD)
  sgemm<96, 96, 24, 2, 0><<<CH * 4, 256, 0, stream>>>(B2, W2, b2, dinv, h2);
  // out = h2 @ Wfc + bfc  (MS=16: 2 slices)
  sgemm<96, 32, 16, 3, 0><<<CH * 2, 256, 0, stream>>>(h2, Wfc, bfc, dinv, out);
}